// Round 11
// baseline (136.314 us; speedup 1.0000x reference)
//
#include <hip/hip_runtime.h>
#include <hip/hip_fp16.h>

// ---------------------------------------------------------------------------
// Round-11 pipeline:
//   memset(counts+gcur, one region) ;
//   convhist (fused fp32->fp16 table conv + bucket minihist) ;
//   bin (computes bucket bases itself from counts -> no scan dispatch;
//        SoA payload gkey/gef; coalesced flush into bucket runs) ;
//   bsort (bucket-local counting sort: node-sorted 4B src array + per-node
//          offsets; accumulates efeat per node, writes out[:,64]) ;
//   gather (1 wave/node, 2 edges/iter via half-wave split, uint(=half2)
//           loads: 16 rows in flight, shfl_xor(32) merge, linear store).
// Key: gkey word = (dst&63)<<17 | src   (needs N <= 2^17).
// ---------------------------------------------------------------------------

#define NB_SHIFT 6
#define BNODES   64           // nodes per bucket
#define SRC_BITS 17
#define SRC_MASK ((1 << SRC_BITS) - 1)
#define BIN_S    4096         // edges per bin/hist block
#define BIN_T    512
#define MAXNB    2048

// Fused: blocks [0, c_blocks) convert the table fp32->fp16 (4096 elems each);
// blocks [c_blocks, ...) histogram dst into NB bucket counts.
__global__ __launch_bounds__(BIN_T) void convhist_kernel(const float* __restrict__ g,
                                                         __half* __restrict__ h,
                                                         int n_emb, int c_blocks,
                                                         const int* __restrict__ dst,
                                                         int* __restrict__ counts,
                                                         int E, int NB) {
    __shared__ int cnt[MAXNB];
    int t = threadIdx.x;

    if (blockIdx.x < c_blocks) {
        int i = (blockIdx.x * BIN_T + t) * 8;
        if (i + 7 < n_emb) {
            float4 a = *(const float4*)(g + i);
            float4 b = *(const float4*)(g + i + 4);
            __half2 h0 = __floats2half2_rn(a.x, a.y);
            __half2 h1 = __floats2half2_rn(a.z, a.w);
            __half2 h2 = __floats2half2_rn(b.x, b.y);
            __half2 h3 = __floats2half2_rn(b.z, b.w);
            int4 o;
            o.x = *(int*)&h0; o.y = *(int*)&h1; o.z = *(int*)&h2; o.w = *(int*)&h3;
            *(int4*)(h + i) = o;
        } else {
            for (int k = i; k < n_emb; ++k) h[k] = __float2half(g[k]);
        }
        return;
    }

    int hb = blockIdx.x - c_blocks;
    for (int i = t; i < MAXNB; i += BIN_T) cnt[i] = 0;
    __syncthreads();
    int e0 = hb * BIN_S + t * 8;
    if (e0 + 7 < E) {
        int4 a = *(const int4*)(dst + e0);
        int4 b = *(const int4*)(dst + e0 + 4);
        atomicAdd(&cnt[a.x >> NB_SHIFT], 1);
        atomicAdd(&cnt[a.y >> NB_SHIFT], 1);
        atomicAdd(&cnt[a.z >> NB_SHIFT], 1);
        atomicAdd(&cnt[a.w >> NB_SHIFT], 1);
        atomicAdd(&cnt[b.x >> NB_SHIFT], 1);
        atomicAdd(&cnt[b.y >> NB_SHIFT], 1);
        atomicAdd(&cnt[b.z >> NB_SHIFT], 1);
        atomicAdd(&cnt[b.w >> NB_SHIFT], 1);
    } else {
        for (int k = e0; k < E; ++k) atomicAdd(&cnt[dst[k] >> NB_SHIFT], 1);
    }
    __syncthreads();
    for (int i = t; i < NB; i += BIN_T)
        if (cnt[i]) atomicAdd(&counts[i], cnt[i]);
}

// bin: per-block scan of global counts (registers) -> bucket bases; local
// rank+scan; stage SoA payloads; reserve via gcur0 (zero-based); flush.
// Block 0 also publishes goff for bsort.
__global__ __launch_bounds__(BIN_T) void bin_kernel(const int* __restrict__ src,
                                                    const float* __restrict__ ef,
                                                    const int* __restrict__ dst,
                                                    const int* __restrict__ counts,
                                                    int* __restrict__ gcur0,
                                                    int* __restrict__ goff,
                                                    int* __restrict__ gkey,
                                                    float* __restrict__ gef,
                                                    int E, int NB) {
    __shared__ int cnt[MAXNB];              // 8 KB
    __shared__ int lbase[MAXNB];            // 8 KB
    __shared__ int wsum[8];
    __shared__ int wbase[8];
    __shared__ int   skey[BIN_S];           // 16 KB
    __shared__ float sef[BIN_S];            // 16 KB
    __shared__ unsigned short sbuck[BIN_S]; // 8 KB  (total ~56 KB)

    const int t    = threadIdx.x;
    const int lane = t & 63;
    const int wv   = t >> 6;

    // ---- phase A: global bucket bases from counts (kept in registers) ----
    int4 gc = *(const int4*)(counts + 4 * t);    // counts area padded to MAXNB
    int gts = gc.x + gc.y + gc.z + gc.w;
    int ginc = gts;
#pragma unroll
    for (int o = 1; o < 64; o <<= 1) {
        int u = __shfl_up(ginc, o);
        if (lane >= o) ginc += u;
    }
    if (lane == 63) wsum[wv] = ginc;
    __syncthreads();
    if (t < 8) {
        int v = wsum[t];
        int inc = v;
#pragma unroll
        for (int o = 1; o < 8; o <<= 1) {
            int u = __shfl_up(inc, o);
            if (t >= o) inc += u;
        }
        wbase[t] = inc - v;
    }
    __syncthreads();
    int gex = wbase[wv] + (ginc - gts);
    int sb0 = gex;
    int sb1 = sb0 + gc.x;
    int sb2 = sb1 + gc.y;
    int sb3 = sb2 + gc.z;
    if (blockIdx.x == 0) {
        if (4 * t     <= NB) goff[4 * t]     = sb0;
        if (4 * t + 1 <= NB) goff[4 * t + 1] = sb1;
        if (4 * t + 2 <= NB) goff[4 * t + 2] = sb2;
        if (4 * t + 3 <= NB) goff[4 * t + 3] = sb3;
    }
    __syncthreads();   // wsum/wbase reused below

    // ---- phase B: local histogram + rank ----
    for (int i = t; i < MAXNB; i += BIN_T) cnt[i] = 0;
    __syncthreads();

    int e0 = blockIdx.x * BIN_S + t * 8;
    int dv[8], sv[8], bk[8], rk[8];
    float ev[8];

    if (e0 + 7 < E) {
        *(int4*)&dv[0]   = *(const int4*)(dst + e0);
        *(int4*)&dv[4]   = *(const int4*)(dst + e0 + 4);
        *(int4*)&sv[0]   = *(const int4*)(src + e0);
        *(int4*)&sv[4]   = *(const int4*)(src + e0 + 4);
        *(float4*)&ev[0] = *(const float4*)(ef + e0);
        *(float4*)&ev[4] = *(const float4*)(ef + e0 + 4);
#pragma unroll
        for (int k = 0; k < 8; ++k) {
            bk[k] = dv[k] >> NB_SHIFT;
            rk[k] = atomicAdd(&cnt[bk[k]], 1);
        }
    } else {
#pragma unroll
        for (int k = 0; k < 8; ++k) {
            if (e0 + k < E) {
                dv[k] = dst[e0 + k];
                sv[k] = src[e0 + k];
                ev[k] = ef[e0 + k];
                bk[k] = dv[k] >> NB_SHIFT;
                rk[k] = atomicAdd(&cnt[bk[k]], 1);
            } else {
                bk[k] = -1;
            }
        }
    }
    __syncthreads();

    // local exclusive scan of cnt (4/thread, shfl)
    int c0 = cnt[4 * t], c1 = cnt[4 * t + 1], c2 = cnt[4 * t + 2], c3 = cnt[4 * t + 3];
    int ts = c0 + c1 + c2 + c3;
    int incl = ts;
#pragma unroll
    for (int o = 1; o < 64; o <<= 1) {
        int u = __shfl_up(incl, o);
        if (lane >= o) incl += u;
    }
    if (lane == 63) wsum[wv] = incl;
    __syncthreads();
    if (t < 8) {
        int v = wsum[t];
        int inc = v;
#pragma unroll
        for (int o = 1; o < 8; o <<= 1) {
            int u = __shfl_up(inc, o);
            if (t >= o) inc += u;
        }
        wbase[t] = inc - v;
    }
    __syncthreads();
    int ex  = wbase[wv] + (incl - ts);
    int lb0 = ex;
    int lb1 = lb0 + c0;
    int lb2 = lb1 + c1;
    int lb3 = lb2 + c2;
    lbase[4 * t]     = lb0;
    lbase[4 * t + 1] = lb1;
    lbase[4 * t + 2] = lb2;
    lbase[4 * t + 3] = lb3;
    __syncthreads();

    // stage ranked payloads (SoA)
#pragma unroll
    for (int k = 0; k < 8; ++k) {
        if (bk[k] >= 0) {
            int pos = lbase[bk[k]] + rk[k];
            skey[pos]  = ((dv[k] & (BNODES - 1)) << SRC_BITS) | sv[k];
            sef[pos]   = ev[k];
            sbuck[pos] = (unsigned short)bk[k];
        }
    }
    // reserve per bucket: flush offset f = global_pos - local_pos, into cnt[]
    {
        int f;
        f = (c0 ? sb0 + atomicAdd(&gcur0[4 * t],     c0) : 0) - lb0; cnt[4 * t]     = f;
        f = (c1 ? sb1 + atomicAdd(&gcur0[4 * t + 1], c1) : 0) - lb1; cnt[4 * t + 1] = f;
        f = (c2 ? sb2 + atomicAdd(&gcur0[4 * t + 2], c2) : 0) - lb2; cnt[4 * t + 2] = f;
        f = (c3 ? sb3 + atomicAdd(&gcur0[4 * t + 3], c3) : 0) - lb3; cnt[4 * t + 3] = f;
    }
    __syncthreads();

    // coalesced flush
    int s_total = min(BIN_S, E - blockIdx.x * BIN_S);
    for (int i = t; i < s_total; i += BIN_T) {
        int b = sbuck[i];
        int p = cnt[b] + i;
        gkey[p] = skey[i];
        gef[p]  = sef[i];
    }
}

// Bucket-local counting sort + efeat column. One block per bucket.
__global__ __launch_bounds__(256) void bsort_kernel(const int* __restrict__ gkey,
                                                    const float* __restrict__ gef,
                                                    const int* __restrict__ goff,
                                                    int* __restrict__ gsrc2,
                                                    int* __restrict__ noff,
                                                    float* __restrict__ out,
                                                    int N, int E) {
    __shared__ int   cnt[BNODES];
    __shared__ int   cur[BNODES];
    __shared__ float esum[BNODES];

    const int t  = threadIdx.x;
    const int b  = blockIdx.x;
    const int lo = goff[b];
    const int hi = goff[b + 1];

    if (t < BNODES) { cnt[t] = 0; esum[t] = 0.f; }
    __syncthreads();

    // pass 1: per-node histogram (keys only, contiguous 4B reads)
    for (int i = lo + t; i < hi; i += 256)
        atomicAdd(&cnt[gkey[i] >> SRC_BITS], 1);
    __syncthreads();

    // wave-0 shfl exclusive scan of the 64 counters
    if (t < 64) {
        int v = cnt[t];
        int inc = v;
#pragma unroll
        for (int o = 1; o < 64; o <<= 1) {
            int u = __shfl_up(inc, o);
            if (t >= o) inc += u;
        }
        int base = lo + inc - v;
        cur[t] = base;
        int node = b * BNODES + t;
        if (node <= N) noff[node] = base;
    }
    if (b == 0 && t == 0) noff[N] = E;
    __syncthreads();

    // pass 2: place node-sorted srcs; accumulate efeat per node
    for (int i = lo + t; i < hi; i += 256) {
        int k = gkey[i];
        int r = k >> SRC_BITS;
        int pos = atomicAdd(&cur[r], 1);
        gsrc2[pos] = k & SRC_MASK;
        atomicAdd(&esum[r], gef[i]);
    }
    __syncthreads();

    if (t < 64) {
        int node = b * BNODES + t;
        if (node < N) out[(size_t)node * 65 + 64] = esum[t];
    }
}

// Gather: one wave per node; 2 edges per iteration (half-wave split).
// Lane l: half hl = l>>5 handles edge parity hl; 32 lanes x 4B (half2) per row.
// 8 loads/iter = 16 rows in flight. Final shfl_xor(32) merges halves.
__global__ void gather_h2_kernel(const __half* __restrict__ hg,
                                 const int* __restrict__ gs,
                                 const int* __restrict__ noff,
                                 float* __restrict__ out, int N) {
    int wid  = (blockIdx.x * blockDim.x + threadIdx.x) >> 6;
    int lane = threadIdx.x & 63;
    if (wid >= N) return;

    const unsigned int* __restrict__ hg32 = (const unsigned int*)hg;
    const int hl  = lane >> 5;     // 0: even edges, 1: odd edges
    const int l32 = lane & 31;     // feature pair index

    int beg = noff[wid];
    int end = noff[wid + 1];

    float ax0 = 0.f, ay0 = 0.f, ax1 = 0.f, ay1 = 0.f;
    float ax2 = 0.f, ay2 = 0.f, ax3 = 0.f, ay3 = 0.f;

    int j = beg;
    for (; j + 15 < end; j += 16) {
        int s0 = gs[j +  0 + hl]; int s1 = gs[j +  2 + hl];
        int s2 = gs[j +  4 + hl]; int s3 = gs[j +  6 + hl];
        int s4 = gs[j +  8 + hl]; int s5 = gs[j + 10 + hl];
        int s6 = gs[j + 12 + hl]; int s7 = gs[j + 14 + hl];
        unsigned int u0 = hg32[(size_t)s0 * 32 + l32];
        unsigned int u1 = hg32[(size_t)s1 * 32 + l32];
        unsigned int u2 = hg32[(size_t)s2 * 32 + l32];
        unsigned int u3 = hg32[(size_t)s3 * 32 + l32];
        unsigned int u4 = hg32[(size_t)s4 * 32 + l32];
        unsigned int u5 = hg32[(size_t)s5 * 32 + l32];
        unsigned int u6 = hg32[(size_t)s6 * 32 + l32];
        unsigned int u7 = hg32[(size_t)s7 * 32 + l32];
        __half2 h0 = *(__half2*)&u0; ax0 += __half2float(h0.x); ay0 += __half2float(h0.y);
        __half2 h1 = *(__half2*)&u1; ax1 += __half2float(h1.x); ay1 += __half2float(h1.y);
        __half2 h2 = *(__half2*)&u2; ax2 += __half2float(h2.x); ay2 += __half2float(h2.y);
        __half2 h3 = *(__half2*)&u3; ax3 += __half2float(h3.x); ay3 += __half2float(h3.y);
        __half2 h4 = *(__half2*)&u4; ax0 += __half2float(h4.x); ay0 += __half2float(h4.y);
        __half2 h5 = *(__half2*)&u5; ax1 += __half2float(h5.x); ay1 += __half2float(h5.y);
        __half2 h6 = *(__half2*)&u6; ax2 += __half2float(h6.x); ay2 += __half2float(h6.y);
        __half2 h7 = *(__half2*)&u7; ax3 += __half2float(h7.x); ay3 += __half2float(h7.y);
    }
    for (; j < end; j += 2) {
        int e = j + hl;
        unsigned int u = 0;
        if (e < end) u = hg32[(size_t)gs[e] * 32 + l32];
        __half2 h = *(__half2*)&u;
        ax0 += __half2float(h.x);
        ay0 += __half2float(h.y);
    }

    float ax = (ax0 + ax1) + (ax2 + ax3);
    float ay = (ay0 + ay1) + (ay2 + ay3);
    ax += __shfl_xor(ax, 32);
    ay += __shfl_xor(ay, 32);

    if (lane < 32) {
        size_t base = (size_t)wid * 65 + 2 * l32;
        out[base]     = ax;
        out[base + 1] = ay;
    }
}

// ---------------------- fallback (always correct) --------------------------

__global__ void atomic_fallback_kernel(const float* __restrict__ gemb,
                                       const float* __restrict__ efeat,
                                       const int* __restrict__ src,
                                       const int* __restrict__ dst,
                                       float* __restrict__ out, int E) {
    int eidx = blockIdx.x * 4 + (threadIdx.x >> 6);
    int lane = threadIdx.x & 63;
    if (eidx >= E) return;
    int s = src[eidx];
    int d = dst[eidx];
    float v = gemb[(size_t)s * 64 + lane];
    atomicAdd(&out[(size_t)d * 65 + lane], v);
    if (lane == 0) atomicAdd(&out[(size_t)d * 65 + 64], efeat[eidx]);
}

// ---------------------------------------------------------------------------

extern "C" void kernel_launch(void* const* d_in, const int* in_sizes, int n_in,
                              void* d_out, int out_size, void* d_ws, size_t ws_size,
                              hipStream_t stream) {
    const float* gemb  = (const float*)d_in[0];   // [N, 64]
    const float* efeat = (const float*)d_in[1];   // [E]
    const int*   src   = (const int*)d_in[2];     // [E]
    const int*   dst   = (const int*)d_in[3];     // [E]
    float*       out   = (float*)d_out;           // [N, 65]

    const int N  = in_sizes[0] / 64;
    const int E  = in_sizes[1];
    const int NB = (N + BNODES - 1) >> NB_SHIFT;

    auto aln = [](size_t x) { return (x + 63) & ~(size_t)63; };
    size_t off_counts = 0;                                   // [MAXNB] +
    size_t off_gcur   = off_counts + (size_t)MAXNB * 4;      // [MAXNB] (one memset)
    size_t off_goff   = off_gcur   + (size_t)MAXNB * 4;
    size_t off_noff   = aln(off_goff + (size_t)(NB + 1) * 4);
    size_t off_gkey   = aln(off_noff + (size_t)(N + 1) * 4);
    size_t off_gef    = aln(off_gkey + (size_t)E * 4);
    size_t off_gsrc2  = aln(off_gef  + (size_t)E * 4);
    size_t off_hg     = aln(off_gsrc2 + (size_t)E * 4);
    size_t needed     = off_hg + (size_t)N * 64 * 2;

    if (N > (1 << SRC_BITS) || NB > MAXNB || ws_size < needed) {
        hipMemsetAsync(d_out, 0, (size_t)out_size * sizeof(float), stream);
        int blocks = (E + 3) / 4;
        atomic_fallback_kernel<<<blocks, 256, 0, stream>>>(gemb, efeat, src, dst, out, E);
        return;
    }

    char*   ws     = (char*)d_ws;
    int*    counts = (int*)(ws + off_counts);
    int*    gcur0  = (int*)(ws + off_gcur);
    int*    goff   = (int*)(ws + off_goff);
    int*    noff   = (int*)(ws + off_noff);
    int*    gkey   = (int*)(ws + off_gkey);
    float*  gef    = (float*)(ws + off_gef);
    int*    gsrc2  = (int*)(ws + off_gsrc2);
    __half* hg     = (__half*)(ws + off_hg);

    // single memset covers counts + gcur0 (adjacent)
    hipMemsetAsync(counts, 0, (size_t)MAXNB * 2 * 4, stream);

    int n_emb    = N * 64;
    int c_blocks = (n_emb + BIN_T * 8 - 1) / (BIN_T * 8);
    int h_blocks = (E + BIN_S - 1) / BIN_S;
    convhist_kernel<<<c_blocks + h_blocks, BIN_T, 0, stream>>>(
        gemb, hg, n_emb, c_blocks, dst, counts, E, NB);

    bin_kernel<<<h_blocks, BIN_T, 0, stream>>>(src, efeat, dst, counts,
                                               gcur0, goff, gkey, gef, E, NB);
    bsort_kernel<<<NB, 256, 0, stream>>>(gkey, gef, goff, gsrc2, noff, out, N, E);

    int g_blocks = (N + 3) / 4;
    gather_h2_kernel<<<g_blocks, 256, 0, stream>>>(hg, gsrc2, noff, out, N);
}